// Round 15
// baseline (304.222 us; speedup 1.0000x reference)
//
#include <hip/hip_runtime.h>
#include <hip/hip_fp16.h>
#include <math.h>

#define NN 25000
#define NE 400000
#define HD 64
#define EMBD 8
#define NG 16
#define NC 10
#define SCAN_NB 98   // ceil(NN/256)
#define NSL 16       // stat shadow slices (atomic-contention sharding)
#define STATS_F (NSL * 64 + NSL * 64 + NSL * 1024)   // sumsN + sumsqN + XgN

typedef _Float16 f16x8 __attribute__((ext_vector_type(8)));
typedef float f32x4 __attribute__((ext_vector_type(4)));

// ---------------------------------------------------------------------------
// init_hist_k (R12/R13 fusion, verified):
//   gid < NE        : dst histogram (cnt zeroed by the preceding memset)
//   gid < NN*16     : fp16 shadow of layer-0 features
//   gid < 3*STATS_F : zero the 3 per-layer stats buffers
//   gid < 3*64*512  : Wt fp16 cast+permute (q' = j*8+i channel-major)
//   gid < NG*NC     : zero logits
//   block 0, tx<NG  : gcnt via binary search on sorted gids
// ---------------------------------------------------------------------------
__global__ __launch_bounds__(256) void init_hist_k(const int* __restrict__ dst,
        int* cnt, const float* __restrict__ feature, __half* __restrict__ h16,
        const float* __restrict__ W0, const float* __restrict__ W1,
        const float* __restrict__ W2, __half* __restrict__ Wt,
        float* __restrict__ statsAll, float* __restrict__ out,
        const int* __restrict__ gids, int* gcnt) {
    int gid = blockIdx.x * 256 + threadIdx.x;
    if (gid < NE) atomicAdd(&cnt[dst[gid]], 1);
    if (gid < NN * 16) {
        float4 v = *(const float4*)(feature + (size_t)gid * 4);
        __half2 lo = __floats2half2_rn(v.x, v.y);
        __half2 hi = __floats2half2_rn(v.z, v.w);
        *(__half2*)(h16 + (size_t)gid * 4)     = lo;
        *(__half2*)(h16 + (size_t)gid * 4 + 2) = hi;
    }
    if (gid < 3 * STATS_F) statsAll[gid] = 0.f;
    if (gid < 3 * 64 * 512) {
        int l = gid >> 15;
        int rem = gid & 32767;
        int k = rem >> 9;
        int qp = rem & 511;
        int ii = qp & 7;
        int jj = qp >> 3;
        const float* W = (l == 0) ? W0 : ((l == 1) ? W1 : W2);
        Wt[gid] = __float2half_rn(W[(size_t)(ii * 64 + jj) * 64 + k]);
    }
    if (gid < NG * NC) out[gid] = 0.f;
    if (blockIdx.x == 0 && threadIdx.x < NG) {
        int tx = threadIdx.x;
        int lo = 0, hi = NN;
        while (lo < hi) { int m = (lo + hi) >> 1; if (gids[m] < tx) lo = m + 1; else hi = m; }
        int a = lo;
        lo = 0; hi = NN;
        while (lo < hi) { int m = (lo + hi) >> 1; if (gids[m] < tx + 1) lo = m + 1; else hi = m; }
        gcnt[tx] = lo - a;
    }
}

// ---------------------------------------------------------------------------
// scan_part_k: per-256-node block sums (parallel; R12's serial scan ran 60us).
// ---------------------------------------------------------------------------
__global__ __launch_bounds__(256) void scan_part_k(const int* __restrict__ cnt, int* bsum) {
    __shared__ int sh[256];
    int tx = threadIdx.x;
    int i = blockIdx.x * 256 + tx;
    sh[tx] = (i < NN) ? cnt[i] : 0;
    __syncthreads();
    for (int off = 128; off > 0; off >>= 1) {
        if (tx < off) sh[tx] += sh[tx + off];
        __syncthreads();
    }
    if (tx == 0) bsum[blockIdx.x] = sh[0];
}

// ---------------------------------------------------------------------------
// scan_fm_k: scan_mid merged into scan_final (every block redundantly
// prefix-scans the 98 bsums in LDS; saves one dispatch boundary).
// ---------------------------------------------------------------------------
__global__ __launch_bounds__(256) void scan_fm_k(const int* __restrict__ cnt,
        const int* __restrict__ bsum, int* dstoff, int* cur) {
    __shared__ int sb[128];
    __shared__ int sh[256];
    __shared__ int boff_sh;
    int tx = threadIdx.x;
    if (tx < 128) sb[tx] = (tx < SCAN_NB) ? bsum[tx] : 0;
    __syncthreads();
    for (int off = 1; off < 128; off <<= 1) {
        int t = (tx < 128 && tx >= off) ? sb[tx - off] : 0;
        __syncthreads();
        if (tx < 128) sb[tx] += t;
        __syncthreads();
    }
    if (tx == 0) {
        int b = blockIdx.x;
        boff_sh = (b == 0) ? 0 : sb[b - 1];
        if (b == 0) dstoff[NN] = NE;
    }
    int i = blockIdx.x * 256 + tx;
    int v = (i < NN) ? cnt[i] : 0;
    sh[tx] = v;
    __syncthreads();
    for (int off = 1; off < 256; off <<= 1) {
        int t = (tx >= off) ? sh[tx - off] : 0;
        __syncthreads();
        sh[tx] += t;
        __syncthreads();
    }
    int excl = boff_sh + sh[tx] - v;
    if (i < NN) { dstoff[i] = excl; cur[i] = excl; }
}

// ---------------------------------------------------------------------------
// scatter_k: scatter src to dst-sorted slot + dnorm computation (verified).
// ---------------------------------------------------------------------------
__global__ __launch_bounds__(256) void scatter_k(const int* __restrict__ src,
        const int* __restrict__ dst, const float* __restrict__ c,
        int* cur, int* __restrict__ src_d, float* __restrict__ dnorm_d) {
    int gid = blockIdx.x * 256 + threadIdx.x;
    if (gid >= NE) return;
    int s = src[gid], t = dst[gid];
    int pd = atomicAdd(&cur[t], 1);
    src_d[pd] = s;
    float4 sa = *(const float4*)(c + (size_t)s * 8);
    float4 sb = *(const float4*)(c + (size_t)s * 8 + 4);
    float4 na = *(const float4*)(c + (size_t)t * 8);
    float4 nb = *(const float4*)(c + (size_t)t * 8 + 4);
    float d0 = sa.x - na.x, d1 = sa.y - na.y, d2 = sa.z - na.z, d3 = sa.w - na.w;
    float d4 = sb.x - nb.x, d5 = sb.y - nb.y, d6 = sb.z - nb.z, d7 = sb.w - nb.w;
    float nn2 = d0*d0 + d1*d1 + d2*d2 + d3*d3 + d4*d4 + d5*d5 + d6*d6 + d7*d7;
    float inv = 1.f / fmaxf(sqrtf(nn2), 1e-12f);
    *(float4*)(dnorm_d + (size_t)pd * 8)     = make_float4(d0*inv, d1*inv, d2*inv, d3*inv);
    *(float4*)(dnorm_d + (size_t)pd * 8 + 4) = make_float4(d4*inv, d5*inv, d6*inv, d7*inv);
}

// readlane broadcast of a float held lane-wise (lane index literal after unroll)
__device__ __forceinline__ float rlane(float v, int l) {
    return __uint_as_float((unsigned)__builtin_amdgcn_readlane((int)__float_as_uint(v), l));
}

// ---------------------------------------------------------------------------
// FUSED edge gather + MFMA GEMM.
// R15: cross-node DUAL-STREAM of the R5 ladder. R9 (preamble pipeline,
// neutral) localized the exposed latency to the LOADG->FMAG leg: per node,
// FMAG(g0) stalls one full h16-gather round trip with only 1 group in
// flight, repeated 4x serially per wave. Fix: process nodes in PAIRS with
// the two group-ladders interleaved op-by-op — 32 gathers in flight before
// the first vmcnt wait; stream B's data arrives during stream A's wait.
// Exposed trips per wave: ~4 -> ~2. R1's dual-stream failure mode (broken
// s_load scalarization) doesn't apply: sv is one coalesced load + readlane.
// launch_bounds(256,3): ~170 VGPR budget for ~95 live (spill tripwire =
// WRITE_SIZE). Multi-chunk tails (deg>64, ~absent at Poisson(16)) take a
// serial cold path. Phase 2 (MFMA + stats) unchanged.
// ---------------------------------------------------------------------------
__global__ __launch_bounds__(256, 3) void edge_gemm_k(const int* __restrict__ src_d,
        const int* __restrict__ dstoff, const float* __restrict__ dnorm_d,
        const __half* __restrict__ h16, const __half* __restrict__ Wt16,
        const int* __restrict__ gids, float* __restrict__ agg,
        float* __restrict__ sumsN, float* __restrict__ sumsqN,
        float* __restrict__ XgN) {
    __shared__ __half Esh[16][520];   // padded: 1040B row
    __shared__ float pl[NG * 64];
    __shared__ float s1[64], s2[64];
    __shared__ int gsh[16];
    int tx = threadIdx.x;
    int wave = tx >> 6, lane = tx & 63;
    int n0 = blockIdx.x * 16;
    int slice = blockIdx.x & (NSL - 1);
    const unsigned short* h16u = (const unsigned short*)h16;
    for (int t = tx; t < NG * 64; t += 256) pl[t] = 0.f;
    if (tx < 64) { s1[tx] = 0.f; s2[tx] = 0.f; }
    if (tx < 16) gsh[tx] = gids[min(n0 + tx, NN - 1)];

    // hoisted per-wave CSR ranges (wave-uniform -> SGPRs)
    int P0[4], RM[4];
#pragma unroll
    for (int i = 0; i < 4; i++) {
        int n = n0 + wave * 4 + i;
        int valid = n < NN;
        int nc = valid ? n : 0;
        int a = dstoff[nc];
        int b = dstoff[nc + 1];
        P0[i] = a;
        RM[i] = valid ? (b - a) : 0;
    }

#define PRE(i_, S, DA, DB) do { \
    int hi_ = P0[i_] + max(RM[i_] - 1, 0); \
    int e_ = min(min(P0[i_] + lane, hi_), NE - 1); \
    S = src_d[e_]; \
    DA = *(const float4*)(dnorm_d + (size_t)e_ * 8); \
    DB = *(const float4*)(dnorm_d + (size_t)e_ * 8 + 4); \
} while (0)

#define LG(dst, sv, g) do { _Pragma("unroll") \
    for (int j_ = 0; j_ < 8; j_++) { \
        int s_ = __builtin_amdgcn_readlane(sv, (g) * 8 + j_); \
        dst[j_] = (int)h16u[(size_t)s_ * 64 + lane]; \
    } } while (0)

#define FM(srcv, da, db, e, g, rem) do { _Pragma("unroll") \
    for (int j_ = 0; j_ < 8; j_++) { \
        int jj_ = (g) * 8 + j_; \
        __half hh_; *(unsigned short*)&hh_ = (unsigned short)srcv[j_]; \
        float hv_ = (jj_ < rem) ? __half2float(hh_) : 0.f; \
        e[0] = fmaf(rlane(da.x, jj_), hv_, e[0]); \
        e[1] = fmaf(rlane(da.y, jj_), hv_, e[1]); \
        e[2] = fmaf(rlane(da.z, jj_), hv_, e[2]); \
        e[3] = fmaf(rlane(da.w, jj_), hv_, e[3]); \
        e[4] = fmaf(rlane(db.x, jj_), hv_, e[4]); \
        e[5] = fmaf(rlane(db.y, jj_), hv_, e[5]); \
        e[6] = fmaf(rlane(db.z, jj_), hv_, e[6]); \
        e[7] = fmaf(rlane(db.w, jj_), hv_, e[7]); \
    } } while (0)

    // ---- phase 1: 2 node-pairs per wave, dual-stream ladder ----
    int ps0; float4 pa0, pb0;
    int ps1; float4 pa1, pb1;
    PRE(0, ps0, pa0, pb0);
    PRE(1, ps1, pa1, pb1);
#pragma unroll
    for (int p = 0; p < 2; p++) {
        int iA = p * 2, iB = p * 2 + 1;
        float eA[8] = {0,0,0,0,0,0,0,0}, eB[8] = {0,0,0,0,0,0,0,0};
        int svA = min(max(ps0, 0), NN - 1);
        int svB = min(max(ps1, 0), NN - 1);
        float4 daA = pa0, dbA = pb0, daB = pa1, dbB = pb1;
        int totA = RM[iA], totB = RM[iB];
        if (p == 0) { PRE(2, ps0, pa0, pb0); PRE(3, ps1, pa1, pb1); }
        int remA = totA > 64 ? 64 : totA;
        int remB = totB > 64 ? 64 : totB;
        int hA_A[8], hB_A[8], hA_B[8], hB_B[8];
        // interleaved dual-stream ladder (chunk 0 of both nodes)
        if (totA > 0)  LG(hA_A, svA, 0);
        if (totB > 0)  LG(hA_B, svB, 0);
        if (remA > 8)  LG(hB_A, svA, 1);
        if (remB > 8)  LG(hB_B, svB, 1);
        if (totA > 0)  FM(hA_A, daA, dbA, eA, 0, remA);
        if (remA > 16) LG(hA_A, svA, 2);
        if (totB > 0)  FM(hA_B, daB, dbB, eB, 0, remB);
        if (remB > 16) LG(hA_B, svB, 2);
        if (remA > 8)  FM(hB_A, daA, dbA, eA, 1, remA);
        if (remA > 24) LG(hB_A, svA, 3);
        if (remB > 8)  FM(hB_B, daB, dbB, eB, 1, remB);
        if (remB > 24) LG(hB_B, svB, 3);
        if (remA > 16) FM(hA_A, daA, dbA, eA, 2, remA);
        if (remA > 32) LG(hA_A, svA, 4);
        if (remB > 16) FM(hA_B, daB, dbB, eB, 2, remB);
        if (remB > 32) LG(hA_B, svB, 4);
        if (remA > 24) FM(hB_A, daA, dbA, eA, 3, remA);
        if (remA > 40) LG(hB_A, svA, 5);
        if (remB > 24) FM(hB_B, daB, dbB, eB, 3, remB);
        if (remB > 40) LG(hB_B, svB, 5);
        if (remA > 32) FM(hA_A, daA, dbA, eA, 4, remA);
        if (remA > 48) LG(hA_A, svA, 6);
        if (remB > 32) FM(hA_B, daB, dbB, eB, 4, remB);
        if (remB > 48) LG(hA_B, svB, 6);
        if (remA > 40) FM(hB_A, daA, dbA, eA, 5, remA);
        if (remA > 56) LG(hB_A, svA, 7);
        if (remB > 40) FM(hB_B, daB, dbB, eB, 5, remB);
        if (remB > 56) LG(hB_B, svB, 7);
        if (remA > 48) FM(hA_A, daA, dbA, eA, 6, remA);
        if (remB > 48) FM(hA_B, daB, dbB, eB, 6, remB);
        if (remA > 56) FM(hB_A, daA, dbA, eA, 7, remA);
        if (remB > 56) FM(hB_B, daB, dbB, eB, 7, remB);
        // rare multi-chunk tails (deg>64): serial cold path per stream
        for (int base = 64; base < totA; base += 64) {
            int rem = totA - base; if (rem > 64) rem = 64;
            int e2i = min(P0[iA] + base + lane, P0[iA] + totA - 1);
            int sv = min(max(src_d[e2i], 0), NN - 1);
            float4 da = *(const float4*)(dnorm_d + (size_t)e2i * 8);
            float4 db = *(const float4*)(dnorm_d + (size_t)e2i * 8 + 4);
            LG(hA_A, sv, 0);
            if (rem > 8)  LG(hB_A, sv, 1);
            FM(hA_A, da, db, eA, 0, rem);
            if (rem > 16) LG(hA_A, sv, 2);
            if (rem > 8)  FM(hB_A, da, db, eA, 1, rem);
            if (rem > 24) LG(hB_A, sv, 3);
            if (rem > 16) FM(hA_A, da, db, eA, 2, rem);
            if (rem > 32) LG(hA_A, sv, 4);
            if (rem > 24) FM(hB_A, da, db, eA, 3, rem);
            if (rem > 40) LG(hB_A, sv, 5);
            if (rem > 32) FM(hA_A, da, db, eA, 4, rem);
            if (rem > 48) LG(hA_A, sv, 6);
            if (rem > 40) FM(hB_A, da, db, eA, 5, rem);
            if (rem > 56) LG(hB_A, sv, 7);
            if (rem > 48) FM(hA_A, da, db, eA, 6, rem);
            if (rem > 56) FM(hB_A, da, db, eA, 7, rem);
        }
        for (int base = 64; base < totB; base += 64) {
            int rem = totB - base; if (rem > 64) rem = 64;
            int e2i = min(P0[iB] + base + lane, P0[iB] + totB - 1);
            int sv = min(max(src_d[e2i], 0), NN - 1);
            float4 da = *(const float4*)(dnorm_d + (size_t)e2i * 8);
            float4 db = *(const float4*)(dnorm_d + (size_t)e2i * 8 + 4);
            LG(hA_B, sv, 0);
            if (rem > 8)  LG(hB_B, sv, 1);
            FM(hA_B, da, db, eB, 0, rem);
            if (rem > 16) LG(hA_B, sv, 2);
            if (rem > 8)  FM(hB_B, da, db, eB, 1, rem);
            if (rem > 24) LG(hB_B, sv, 3);
            if (rem > 16) FM(hA_B, da, db, eB, 2, rem);
            if (rem > 32) LG(hA_B, sv, 4);
            if (rem > 24) FM(hB_B, da, db, eB, 3, rem);
            if (rem > 40) LG(hB_B, sv, 5);
            if (rem > 32) FM(hA_B, da, db, eB, 4, rem);
            if (rem > 48) LG(hA_B, sv, 6);
            if (rem > 40) FM(hB_B, da, db, eB, 5, rem);
            if (rem > 56) LG(hB_B, sv, 7);
            if (rem > 48) FM(hA_B, da, db, eB, 6, rem);
            if (rem > 56) FM(hB_B, da, db, eB, 7, rem);
        }
        float4 pack;
        ((__half2*)&pack)[0] = __floats2half2_rn(eA[0], eA[1]);
        ((__half2*)&pack)[1] = __floats2half2_rn(eA[2], eA[3]);
        ((__half2*)&pack)[2] = __floats2half2_rn(eA[4], eA[5]);
        ((__half2*)&pack)[3] = __floats2half2_rn(eA[6], eA[7]);
        *(float4*)&Esh[wave * 4 + iA][lane * 8] = pack;
        ((__half2*)&pack)[0] = __floats2half2_rn(eB[0], eB[1]);
        ((__half2*)&pack)[1] = __floats2half2_rn(eB[2], eB[3]);
        ((__half2*)&pack)[2] = __floats2half2_rn(eB[4], eB[5]);
        ((__half2*)&pack)[3] = __floats2half2_rn(eB[6], eB[7]);
        *(float4*)&Esh[wave * 4 + iB][lane * 8] = pack;
    }
#undef PRE
#undef LG
#undef FM
    __syncthreads();

    // ---- phase 2: MFMA, A from LDS, B from global ----
    int quad = lane >> 4;
    int lcol = lane & 15;
    int c0 = wave * 16;
    const f16x8* pb = (const f16x8*)(Wt16 + (size_t)(c0 + lcol) * 512 + quad * 8);
    f32x4 acc = {0.f, 0.f, 0.f, 0.f};
#pragma unroll
    for (int kc = 0; kc < 16; kc++) {
        f16x8 a = *(const f16x8*)&Esh[lcol][kc * 32 + quad * 8];
        f16x8 b = pb[kc * 4];
        acc = __builtin_amdgcn_mfma_f32_16x16x32_f16(a, b, acc, 0, 0, 0);
    }

    int colg = c0 + lcol;
    float s1l = 0.f, s2l = 0.f;
#pragma unroll
    for (int r = 0; r < 4; r++) {
        int nrow = quad * 4 + r;
        int n = n0 + nrow;
        if (n < NN) {
            float v = acc[r];
            agg[(size_t)n * 64 + colg] = v;
            float x = fmaxf(v, 0.f);
            s1l += x; s2l += x * x;
            atomicAdd(&pl[gsh[nrow] * 64 + colg], x);
        }
    }
    atomicAdd(&s1[colg], s1l);
    atomicAdd(&s2[colg], s2l);
    __syncthreads();
    if (tx < 64) {
        atomicAdd(&sumsN[slice * 64 + tx], s1[tx]);
        atomicAdd(&sumsqN[slice * 64 + tx], s2[tx]);
    }
    for (int t = tx; t < NG * 64; t += 256) {
        float v = pl[t];
        if (v != 0.f) atomicAdd(&XgN[slice * 1024 + t], v);
    }
}

// ---------------------------------------------------------------------------
// Classifier via pooled-BN identity; stats summed over NSL shadow slices.
// ---------------------------------------------------------------------------
__device__ __forceinline__ void classifier_body(int tx,
        const float* __restrict__ sumsN, const float* __restrict__ sumsqN,
        const float* __restrict__ XgN, const int* __restrict__ gcnt,
        float* __restrict__ Pold,
        const float* __restrict__ gamma, const float* __restrict__ beta,
        const float* __restrict__ cW1, const float* __restrict__ cb1,
        const float* __restrict__ cg1, const float* __restrict__ cbt1,
        const float* __restrict__ cW2, const float* __restrict__ cb2,
        float* __restrict__ logits, int sc) {
    __shared__ float Pn[NG * 64];
    __shared__ float H1s[NG * 32];
    __shared__ float cmu[32], crs[32];
    for (int t = tx; t < NG * 64; t += 256) {
        int g = t >> 6, k = t & 63;
        float sk = 0.f, sq = 0.f, xg = 0.f;
#pragma unroll
        for (int s = 0; s < NSL; s++) {
            sk += sumsN[s * 64 + k];
            sq += sumsqN[s * 64 + k];
            xg += XgN[s * 1024 + t];
        }
        float mean = sk * (1.f / NN);
        float var  = sq * (1.f / NN) - mean * mean;
        float r = rsqrtf(var + 1e-5f);
        float cg = (float)gcnt[g];
        float v = gamma[k] * r * (xg - cg * mean) + cg * beta[k];
        if (sc) v += Pold[t];
        Pn[t] = v;
        Pold[t] = v;
    }
    __syncthreads();
    for (int t = tx; t < NG * 32; t += 256) {
        int g = t >> 5, c = t & 31;
        float acc = cb1[c];
#pragma unroll 16
        for (int j = 0; j < 64; j++) acc = fmaf(Pn[g * 64 + j], cW1[j * 32 + c], acc);
        H1s[t] = acc;
    }
    __syncthreads();
    if (tx < 32) {
        float mu = 0.f;
#pragma unroll
        for (int g2 = 0; g2 < NG; g2++) mu += H1s[g2 * 32 + tx];
        mu *= (1.f / NG);
        float v = 0.f;
#pragma unroll
        for (int g2 = 0; g2 < NG; g2++) {
            float d = H1s[g2 * 32 + tx] - mu;
            v += d * d;
        }
        v *= (1.f / NG);
        cmu[tx] = mu;
        crs[tx] = rsqrtf(v + 1e-5f);
    }
    __syncthreads();
    for (int t = tx; t < NG * 32; t += 256) {
        int c = t & 31;
        H1s[t] = fmaxf(cg1[c] * (H1s[t] - cmu[c]) * crs[c] + cbt1[c], 0.f);
    }
    __syncthreads();
    if (tx < NG * NC) {
        int g = tx / NC, cls = tx % NC;
        float a2 = cb2[cls];
#pragma unroll
        for (int j = 0; j < 32; j++) a2 = fmaf(H1s[g * 32 + j], cW2[j * NC + cls], a2);
        logits[tx] += a2;
    }
}

// ---------------------------------------------------------------------------
// bn_apply_k: h16 is the only carried state (R14). Reads agg (fp32) and,
// for shortcut, the OLD h16 (same element, same thread -> no hazard); writes
// only the new h16. Block 0 also runs the classifier.
// ---------------------------------------------------------------------------
__global__ __launch_bounds__(256) void bn_apply_k(const float* __restrict__ agg,
        const float* __restrict__ sumsN, const float* __restrict__ sumsqN,
        const float* __restrict__ gamma, const float* __restrict__ beta,
        __half* __restrict__ h16, int shortcut,
        const float* __restrict__ XgN, const int* __restrict__ gcnt,
        float* __restrict__ Pold,
        const float* __restrict__ cW1, const float* __restrict__ cb1,
        const float* __restrict__ cg1, const float* __restrict__ cbt1,
        const float* __restrict__ cW2, const float* __restrict__ cb2,
        float* __restrict__ logits) {
    int tx = threadIdx.x;
    int col0 = (tx & 15) * 4;
    float mean[4], rstd[4], gv[4], bv[4];
#pragma unroll
    for (int cc = 0; cc < 4; cc++) {
        int k = col0 + cc;
        float sk = 0.f, sq = 0.f;
#pragma unroll
        for (int s = 0; s < NSL; s++) {
            sk += sumsN[s * 64 + k];
            sq += sumsqN[s * 64 + k];
        }
        float mu = sk * (1.f / NN);
        float var = sq * (1.f / NN) - mu * mu;
        mean[cc] = mu;
        rstd[cc] = rsqrtf(var + 1e-5f);
        gv[cc] = gamma[k];
        bv[cc] = beta[k];
    }
    int row = blockIdx.x * 16 + (tx >> 4);
    int rstride = gridDim.x * 16;
    for (int n = row; n < NN; n += rstride) {
        float4 x4 = *(const float4*)(agg + (size_t)n * 64 + col0);
        float y[4] = {x4.x, x4.y, x4.z, x4.w};
#pragma unroll
        for (int cc = 0; cc < 4; cc++) {
            float x = fmaxf(y[cc], 0.f);
            y[cc] = gv[cc] * (x - mean[cc]) * rstd[cc] + bv[cc];
        }
        if (shortcut) {
            float2 hp = *(const float2*)(h16 + (size_t)n * 64 + col0);
            __half2 h0 = ((__half2*)&hp)[0];
            __half2 h1 = ((__half2*)&hp)[1];
            y[0] += __half2float(__low2half(h0));
            y[1] += __half2float(__high2half(h0));
            y[2] += __half2float(__low2half(h1));
            y[3] += __half2float(__high2half(h1));
        }
        float2 pk;
        ((__half2*)&pk)[0] = __floats2half2_rn(y[0], y[1]);
        ((__half2*)&pk)[1] = __floats2half2_rn(y[2], y[3]);
        *(float2*)(h16 + (size_t)n * 64 + col0) = pk;
    }
    if (blockIdx.x == 0)
        classifier_body(tx, sumsN, sumsqN, XgN, gcnt, Pold, gamma, beta,
                        cW1, cb1, cg1, cbt1, cW2, cb2, logits, shortcut);
}

// Layer 2: h_new never consumed -> classifier only (1 block).
__global__ __launch_bounds__(256) void classifier_only_k(
        const float* __restrict__ sumsN, const float* __restrict__ sumsqN,
        const float* __restrict__ XgN, const int* __restrict__ gcnt,
        float* __restrict__ Pold,
        const float* __restrict__ gamma, const float* __restrict__ beta,
        const float* __restrict__ cW1, const float* __restrict__ cb1,
        const float* __restrict__ cg1, const float* __restrict__ cbt1,
        const float* __restrict__ cW2, const float* __restrict__ cb2,
        float* __restrict__ logits) {
    classifier_body(threadIdx.x, sumsN, sumsqN, XgN, gcnt, Pold, gamma, beta,
                    cW1, cb1, cg1, cbt1, cW2, cb2, logits, 1);
}

// ---------------------------------------------------------------------------
extern "C" void kernel_launch(void* const* d_in, const int* in_sizes, int n_in,
                              void* d_out, int out_size, void* d_ws, size_t ws_size,
                              hipStream_t stream) {
    const float* feature = (const float*)d_in[0];
    const float* cemb    = (const float*)d_in[1];
    const int*   src     = (const int*)d_in[2];
    const int*   dst     = (const int*)d_in[3];
    const int*   gids    = (const int*)d_in[4];
    const float* W[3]    = {(const float*)d_in[5], (const float*)d_in[6], (const float*)d_in[7]};
    const float* gam[3]  = {(const float*)d_in[8], (const float*)d_in[10], (const float*)d_in[12]};
    const float* bet[3]  = {(const float*)d_in[9], (const float*)d_in[11], (const float*)d_in[13]};
    const float* cW1  = (const float*)d_in[14];
    const float* cb1  = (const float*)d_in[15];
    const float* cg1  = (const float*)d_in[16];
    const float* cbt1 = (const float*)d_in[17];
    const float* cW2  = (const float*)d_in[18];
    const float* cb2  = (const float*)d_in[19];
    float* out = (float*)d_out;

    // workspace layout (4-byte units)
    float* ws       = (float*)d_ws;
    float* dnorm_d  = ws;                          // NE*8 = 3.2M
    float* bufX     = dnorm_d + (size_t)NE * 8;    // NN*64 (agg, all layers)
    float* bufY     = bufX + (size_t)NN * 64;      // NN*64 (unused)
    float* statsAll = bufY + (size_t)NN * 64;      // 3*STATS_F (zeroed in init)
    float* Pold     = statsAll + 3 * STATS_F;      // 1024 (persists across layers)
    int*   cnt      = (int*)(Pold + 1024);         // NN
    int*   gcnt     = cnt + NN;                    // 16
    int*   cur      = gcnt + 16;                   // NN
    int*   dstoff   = cur + NN;                    // NN+1 (pad +8)
    int*   bsum     = dstoff + NN + 8;             // 128
    int*   boff     = bsum + 128;                  // 128 (unused)
    int*   src_d    = boff + 128;                  // NE
    __half* h16     = (__half*)(src_d + NE);       // NN*64 halfs
    __half* Wt16    = (__half*)((float*)(src_d + NE) + (size_t)NN * 32);  // 3*64*512 halfs

    hipMemsetAsync(cnt, 0, NN * sizeof(int), stream);

    init_hist_k<<<(NE + 255) / 256, 256, 0, stream>>>(dst, cnt, feature, h16,
                                                      W[0], W[1], W[2], Wt16,
                                                      statsAll, out, gids, gcnt);
    scan_part_k<<<SCAN_NB, 256, 0, stream>>>(cnt, bsum);
    scan_fm_k<<<SCAN_NB, 256, 0, stream>>>(cnt, bsum, dstoff, cur);
    scatter_k<<<(NE + 255) / 256, 256, 0, stream>>>(src, dst, cemb, cur, src_d, dnorm_d);

    for (int l = 0; l < 3; l++) {
        float* agg    = bufX;
        float* sumsN  = statsAll + (size_t)l * STATS_F;
        float* sumsqN = sumsN + NSL * 64;
        float* XgN    = sumsqN + NSL * 64;

        edge_gemm_k<<<(NN + 15) / 16, 256, 0, stream>>>(src_d, dstoff, dnorm_d, h16,
                                                        Wt16 + (size_t)l * 64 * 512,
                                                        gids, agg, sumsN, sumsqN, XgN);
        if (l < 2) {
            bn_apply_k<<<1024, 256, 0, stream>>>(agg, sumsN, sumsqN, gam[l], bet[l],
                                                 h16, l > 0, XgN, gcnt, Pold,
                                                 cW1, cb1, cg1, cbt1, cW2, cb2, out);
        } else {
            classifier_only_k<<<1, 256, 0, stream>>>(sumsN, sumsqN, XgN, gcnt, Pold,
                                                     gam[l], bet[l],
                                                     cW1, cb1, cg1, cbt1, cW2, cb2, out);
        }
    }
}

// Round 16
// 300.843 us; speedup vs baseline: 1.0112x; 1.0112x over previous
//
#include <hip/hip_runtime.h>
#include <hip/hip_fp16.h>
#include <math.h>

#define NN 25000
#define NE 400000
#define HD 64
#define EMBD 8
#define NG 16
#define NC 10
#define SCAN_NB 98   // ceil(NN/256)
#define NSL 16       // stat shadow slices (atomic-contention sharding)
#define STATS_F (NSL * 64 + NSL * 64 + NSL * 1024)   // sumsN + sumsqN + XgN

typedef _Float16 f16x8 __attribute__((ext_vector_type(8)));
typedef float f32x4 __attribute__((ext_vector_type(4)));

// ---------------------------------------------------------------------------
// init_hist_k (R12/R13 fusion, verified):
//   gid < NE        : dst histogram (cnt zeroed by the preceding memset)
//   gid < NN*16     : fp16 shadow of layer-0 features
//   gid < 3*STATS_F : zero the 3 per-layer stats buffers
//   gid < 3*64*512  : Wt fp16 cast+permute (q' = j*8+i channel-major)
//   gid < NG*NC     : zero logits
//   block 0, tx<NG  : gcnt via binary search on sorted gids
// ---------------------------------------------------------------------------
__global__ __launch_bounds__(256) void init_hist_k(const int* __restrict__ dst,
        int* cnt, const float* __restrict__ feature, __half* __restrict__ h16,
        const float* __restrict__ W0, const float* __restrict__ W1,
        const float* __restrict__ W2, __half* __restrict__ Wt,
        float* __restrict__ statsAll, float* __restrict__ out,
        const int* __restrict__ gids, int* gcnt) {
    int gid = blockIdx.x * 256 + threadIdx.x;
    if (gid < NE) atomicAdd(&cnt[dst[gid]], 1);
    if (gid < NN * 16) {
        float4 v = *(const float4*)(feature + (size_t)gid * 4);
        __half2 lo = __floats2half2_rn(v.x, v.y);
        __half2 hi = __floats2half2_rn(v.z, v.w);
        *(__half2*)(h16 + (size_t)gid * 4)     = lo;
        *(__half2*)(h16 + (size_t)gid * 4 + 2) = hi;
    }
    if (gid < 3 * STATS_F) statsAll[gid] = 0.f;
    if (gid < 3 * 64 * 512) {
        int l = gid >> 15;
        int rem = gid & 32767;
        int k = rem >> 9;
        int qp = rem & 511;
        int ii = qp & 7;
        int jj = qp >> 3;
        const float* W = (l == 0) ? W0 : ((l == 1) ? W1 : W2);
        Wt[gid] = __float2half_rn(W[(size_t)(ii * 64 + jj) * 64 + k]);
    }
    if (gid < NG * NC) out[gid] = 0.f;
    if (blockIdx.x == 0 && threadIdx.x < NG) {
        int tx = threadIdx.x;
        int lo = 0, hi = NN;
        while (lo < hi) { int m = (lo + hi) >> 1; if (gids[m] < tx) lo = m + 1; else hi = m; }
        int a = lo;
        lo = 0; hi = NN;
        while (lo < hi) { int m = (lo + hi) >> 1; if (gids[m] < tx + 1) lo = m + 1; else hi = m; }
        gcnt[tx] = lo - a;
    }
}

// ---------------------------------------------------------------------------
// Parallel 3-kernel scan (R12's single-block scan ran 60us; this never
// registered in a top-5).
// ---------------------------------------------------------------------------
__global__ __launch_bounds__(256) void scan_part_k(const int* __restrict__ cnt, int* bsum) {
    __shared__ int sh[256];
    int tx = threadIdx.x;
    int i = blockIdx.x * 256 + tx;
    sh[tx] = (i < NN) ? cnt[i] : 0;
    __syncthreads();
    for (int off = 128; off > 0; off >>= 1) {
        if (tx < off) sh[tx] += sh[tx + off];
        __syncthreads();
    }
    if (tx == 0) bsum[blockIdx.x] = sh[0];
}

__global__ __launch_bounds__(128) void scan_mid_k(const int* __restrict__ bsum,
        int* boff, int* dstoff) {
    __shared__ int sh[128];
    int tx = threadIdx.x;
    int v = (tx < SCAN_NB) ? bsum[tx] : 0;
    sh[tx] = v;
    __syncthreads();
    for (int off = 1; off < 128; off <<= 1) {
        int t = (tx >= off) ? sh[tx - off] : 0;
        __syncthreads();
        sh[tx] += t;
        __syncthreads();
    }
    if (tx < SCAN_NB) boff[tx] = sh[tx] - v;
    if (tx == 0) dstoff[NN] = NE;
}

__global__ __launch_bounds__(256) void scan_final_k(const int* __restrict__ cnt,
        const int* __restrict__ boff, int* dstoff, int* cur) {
    __shared__ int sh[256];
    int tx = threadIdx.x;
    int i = blockIdx.x * 256 + tx;
    int v = (i < NN) ? cnt[i] : 0;
    sh[tx] = v;
    __syncthreads();
    for (int off = 1; off < 256; off <<= 1) {
        int t = (tx >= off) ? sh[tx - off] : 0;
        __syncthreads();
        sh[tx] += t;
        __syncthreads();
    }
    int excl = boff[blockIdx.x] + sh[tx] - v;
    if (i < NN) { dstoff[i] = excl; cur[i] = excl; }
}

// ---------------------------------------------------------------------------
// scatter_k: scatter src to dst-sorted slot + dnorm computation (verified).
// ---------------------------------------------------------------------------
__global__ __launch_bounds__(256) void scatter_k(const int* __restrict__ src,
        const int* __restrict__ dst, const float* __restrict__ c,
        int* cur, int* __restrict__ src_d, float* __restrict__ dnorm_d) {
    int gid = blockIdx.x * 256 + threadIdx.x;
    if (gid >= NE) return;
    int s = src[gid], t = dst[gid];
    int pd = atomicAdd(&cur[t], 1);
    src_d[pd] = s;
    float4 sa = *(const float4*)(c + (size_t)s * 8);
    float4 sb = *(const float4*)(c + (size_t)s * 8 + 4);
    float4 na = *(const float4*)(c + (size_t)t * 8);
    float4 nb = *(const float4*)(c + (size_t)t * 8 + 4);
    float d0 = sa.x - na.x, d1 = sa.y - na.y, d2 = sa.z - na.z, d3 = sa.w - na.w;
    float d4 = sb.x - nb.x, d5 = sb.y - nb.y, d6 = sb.z - nb.z, d7 = sb.w - nb.w;
    float nn2 = d0*d0 + d1*d1 + d2*d2 + d3*d3 + d4*d4 + d5*d5 + d6*d6 + d7*d7;
    float inv = 1.f / fmaxf(sqrtf(nn2), 1e-12f);
    *(float4*)(dnorm_d + (size_t)pd * 8)     = make_float4(d0*inv, d1*inv, d2*inv, d3*inv);
    *(float4*)(dnorm_d + (size_t)pd * 8 + 4) = make_float4(d4*inv, d5*inv, d6*inv, d7*inv);
}

// readlane broadcast of a float held lane-wise (lane index literal after unroll)
__device__ __forceinline__ float rlane(float v, int l) {
    return __uint_as_float((unsigned)__builtin_amdgcn_readlane((int)__float_as_uint(v), l));
}

// ---------------------------------------------------------------------------
// FUSED edge gather + MFMA GEMM — R9 body verbatim (equal-best 42.4-43us).
// FROZEN: R1/R2/R6/R8/R9/R15 all refuted restructuring (dual-stream x2,
// chain-length x3, preamble pipeline); 43us is this gather's floor here.
// ---------------------------------------------------------------------------
__global__ __launch_bounds__(256, 4) void edge_gemm_k(const int* __restrict__ src_d,
        const int* __restrict__ dstoff, const float* __restrict__ dnorm_d,
        const __half* __restrict__ h16, const __half* __restrict__ Wt16,
        const int* __restrict__ gids, float* __restrict__ agg,
        float* __restrict__ sumsN, float* __restrict__ sumsqN,
        float* __restrict__ XgN) {
    __shared__ __half Esh[16][520];   // padded: 1040B row
    __shared__ float pl[NG * 64];
    __shared__ float s1[64], s2[64];
    __shared__ int gsh[16];
    int tx = threadIdx.x;
    int wave = tx >> 6, lane = tx & 63;
    int n0 = blockIdx.x * 16;
    int slice = blockIdx.x & (NSL - 1);
    const unsigned short* h16u = (const unsigned short*)h16;
    for (int t = tx; t < NG * 64; t += 256) pl[t] = 0.f;
    if (tx < 64) { s1[tx] = 0.f; s2[tx] = 0.f; }
    if (tx < 16) gsh[tx] = gids[min(n0 + tx, NN - 1)];

    // hoisted per-wave CSR ranges (wave-uniform -> SGPRs)
    int P0[4], RM[4];
#pragma unroll
    for (int i = 0; i < 4; i++) {
        int n = n0 + wave * 4 + i;
        int valid = n < NN;
        int nc = valid ? n : 0;
        int a = dstoff[nc];
        int b = dstoff[nc + 1];
        P0[i] = a;
        RM[i] = valid ? (b - a) : 0;
    }

#define PRELOAD(i_) do { \
    int hi_ = P0[i_] + max(RM[i_] - 1, 0); \
    int e_ = min(min(P0[i_] + lane, hi_), NE - 1); \
    nsv = src_d[e_]; \
    nda = *(const float4*)(dnorm_d + (size_t)e_ * 8); \
    ndb = *(const float4*)(dnorm_d + (size_t)e_ * 8 + 4); \
} while (0)

#define LOADG(dst, g) do { _Pragma("unroll") \
    for (int j_ = 0; j_ < 8; j_++) { \
        int s_ = __builtin_amdgcn_readlane(sv_c, (g) * 8 + j_); \
        dst[j_] = (int)h16u[(size_t)s_ * 64 + lane]; \
    } } while (0)

#define FMAG(srcv, g) do { _Pragma("unroll") \
    for (int j_ = 0; j_ < 8; j_++) { \
        int jj_ = (g) * 8 + j_; \
        __half hh_; *(unsigned short*)&hh_ = (unsigned short)srcv[j_]; \
        float hv_ = (jj_ < rem) ? __half2float(hh_) : 0.f; \
        e0 = fmaf(rlane(da_c.x, jj_), hv_, e0); \
        e1 = fmaf(rlane(da_c.y, jj_), hv_, e1); \
        e2 = fmaf(rlane(da_c.z, jj_), hv_, e2); \
        e3 = fmaf(rlane(da_c.w, jj_), hv_, e3); \
        e4 = fmaf(rlane(db_c.x, jj_), hv_, e4); \
        e5 = fmaf(rlane(db_c.y, jj_), hv_, e5); \
        e6 = fmaf(rlane(db_c.z, jj_), hv_, e6); \
        e7 = fmaf(rlane(db_c.w, jj_), hv_, e7); \
    } } while (0)

    // ---- phase 1: 4 nodes per wave, cross-node pipelined preamble ----
    int nsv; float4 nda, ndb;
    PRELOAD(0);
#pragma unroll
    for (int i = 0; i < 4; i++) {
        float e0=0,e1=0,e2=0,e3=0,e4=0,e5=0,e6=0,e7=0;
        int sv_c = min(max(nsv, 0), NN - 1);   // consume prefetch (clamped safe)
        float4 da_c = nda, db_c = ndb;
        int tot = RM[i];
        if (i < 3) PRELOAD(i + 1);             // issue next node's preamble NOW
        for (int base = 0; base < tot; base += 64) {
            int rem = tot - base; if (rem > 64) rem = 64;
            if (base > 0) {                    // cold path: multi-chunk tail
                int e2i = min(P0[i] + base + lane, P0[i] + tot - 1);
                sv_c = min(max(src_d[e2i], 0), NN - 1);
                da_c = *(const float4*)(dnorm_d + (size_t)e2i * 8);
                db_c = *(const float4*)(dnorm_d + (size_t)e2i * 8 + 4);
            }
            int hA[8], hB[8];
            LOADG(hA, 0);
            if (rem > 8)  LOADG(hB, 1);
            FMAG(hA, 0);
            if (rem > 16) LOADG(hA, 2);
            if (rem > 8)  FMAG(hB, 1);
            if (rem > 24) LOADG(hB, 3);
            if (rem > 16) FMAG(hA, 2);
            if (rem > 32) LOADG(hA, 4);
            if (rem > 24) FMAG(hB, 3);
            if (rem > 40) LOADG(hB, 5);
            if (rem > 32) FMAG(hA, 4);
            if (rem > 48) LOADG(hA, 6);
            if (rem > 40) FMAG(hB, 5);
            if (rem > 56) LOADG(hB, 7);
            if (rem > 48) FMAG(hA, 6);
            if (rem > 56) FMAG(hB, 7);
        }
        float4 pack;
        ((__half2*)&pack)[0] = __floats2half2_rn(e0, e1);
        ((__half2*)&pack)[1] = __floats2half2_rn(e2, e3);
        ((__half2*)&pack)[2] = __floats2half2_rn(e4, e5);
        ((__half2*)&pack)[3] = __floats2half2_rn(e6, e7);
        *(float4*)&Esh[wave * 4 + i][lane * 8] = pack;
    }
#undef PRELOAD
#undef LOADG
#undef FMAG
    __syncthreads();

    // ---- phase 2: MFMA, A from LDS, B from global ----
    int quad = lane >> 4;
    int lcol = lane & 15;
    int c0 = wave * 16;
    const f16x8* pb = (const f16x8*)(Wt16 + (size_t)(c0 + lcol) * 512 + quad * 8);
    f32x4 acc = {0.f, 0.f, 0.f, 0.f};
#pragma unroll
    for (int kc = 0; kc < 16; kc++) {
        f16x8 a = *(const f16x8*)&Esh[lcol][kc * 32 + quad * 8];
        f16x8 b = pb[kc * 4];
        acc = __builtin_amdgcn_mfma_f32_16x16x32_f16(a, b, acc, 0, 0, 0);
    }

    int colg = c0 + lcol;
    float s1l = 0.f, s2l = 0.f;
#pragma unroll
    for (int r = 0; r < 4; r++) {
        int nrow = quad * 4 + r;
        int n = n0 + nrow;
        if (n < NN) {
            float v = acc[r];
            agg[(size_t)n * 64 + colg] = v;
            float x = fmaxf(v, 0.f);
            s1l += x; s2l += x * x;
            atomicAdd(&pl[gsh[nrow] * 64 + colg], x);
        }
    }
    atomicAdd(&s1[colg], s1l);
    atomicAdd(&s2[colg], s2l);
    __syncthreads();
    if (tx < 64) {
        atomicAdd(&sumsN[slice * 64 + tx], s1[tx]);
        atomicAdd(&sumsqN[slice * 64 + tx], s2[tx]);
    }
    for (int t = tx; t < NG * 64; t += 256) {
        float v = pl[t];
        if (v != 0.f) atomicAdd(&XgN[slice * 1024 + t], v);
    }
}

// ---------------------------------------------------------------------------
// Classifier via pooled-BN identity; stats summed over NSL shadow slices.
// ---------------------------------------------------------------------------
__device__ __forceinline__ void classifier_body(int tx,
        const float* __restrict__ sumsN, const float* __restrict__ sumsqN,
        const float* __restrict__ XgN, const int* __restrict__ gcnt,
        float* __restrict__ Pold,
        const float* __restrict__ gamma, const float* __restrict__ beta,
        const float* __restrict__ cW1, const float* __restrict__ cb1,
        const float* __restrict__ cg1, const float* __restrict__ cbt1,
        const float* __restrict__ cW2, const float* __restrict__ cb2,
        float* __restrict__ logits, int sc) {
    __shared__ float Pn[NG * 64];
    __shared__ float H1s[NG * 32];
    __shared__ float cmu[32], crs[32];
    for (int t = tx; t < NG * 64; t += 256) {
        int g = t >> 6, k = t & 63;
        float sk = 0.f, sq = 0.f, xg = 0.f;
#pragma unroll
        for (int s = 0; s < NSL; s++) {
            sk += sumsN[s * 64 + k];
            sq += sumsqN[s * 64 + k];
            xg += XgN[s * 1024 + t];
        }
        float mean = sk * (1.f / NN);
        float var  = sq * (1.f / NN) - mean * mean;
        float r = rsqrtf(var + 1e-5f);
        float cg = (float)gcnt[g];
        float v = gamma[k] * r * (xg - cg * mean) + cg * beta[k];
        if (sc) v += Pold[t];
        Pn[t] = v;
        Pold[t] = v;
    }
    __syncthreads();
    for (int t = tx; t < NG * 32; t += 256) {
        int g = t >> 5, c = t & 31;
        float acc = cb1[c];
#pragma unroll 16
        for (int j = 0; j < 64; j++) acc = fmaf(Pn[g * 64 + j], cW1[j * 32 + c], acc);
        H1s[t] = acc;
    }
    __syncthreads();
    if (tx < 32) {
        float mu = 0.f;
#pragma unroll
        for (int g2 = 0; g2 < NG; g2++) mu += H1s[g2 * 32 + tx];
        mu *= (1.f / NG);
        float v = 0.f;
#pragma unroll
        for (int g2 = 0; g2 < NG; g2++) {
            float d = H1s[g2 * 32 + tx] - mu;
            v += d * d;
        }
        v *= (1.f / NG);
        cmu[tx] = mu;
        crs[tx] = rsqrtf(v + 1e-5f);
    }
    __syncthreads();
    for (int t = tx; t < NG * 32; t += 256) {
        int c = t & 31;
        H1s[t] = fmaxf(cg1[c] * (H1s[t] - cmu[c]) * crs[c] + cbt1[c], 0.f);
    }
    __syncthreads();
    if (tx < NG * NC) {
        int g = tx / NC, cls = tx % NC;
        float a2 = cb2[cls];
#pragma unroll
        for (int j = 0; j < 32; j++) a2 = fmaf(H1s[g * 32 + j], cW2[j * NC + cls], a2);
        logits[tx] += a2;
    }
}

// ---------------------------------------------------------------------------
// K4: BN apply + shortcut -> h_new (fp32) + fp16 shadow; float4 I/O;
// block 0 also runs the classifier.
// ---------------------------------------------------------------------------
__global__ __launch_bounds__(256) void bn_apply_k(const float* __restrict__ agg,
        const float* __restrict__ h_old, const float* __restrict__ sumsN,
        const float* __restrict__ sumsqN, const float* __restrict__ gamma,
        const float* __restrict__ beta, float* __restrict__ h_new,
        __half* __restrict__ h16_out, int shortcut,
        const float* __restrict__ XgN, const int* __restrict__ gcnt,
        float* __restrict__ Pold,
        const float* __restrict__ cW1, const float* __restrict__ cb1,
        const float* __restrict__ cg1, const float* __restrict__ cbt1,
        const float* __restrict__ cW2, const float* __restrict__ cb2,
        float* __restrict__ logits) {
    int tx = threadIdx.x;
    int col0 = (tx & 15) * 4;
    float mean[4], rstd[4], gv[4], bv[4];
#pragma unroll
    for (int cc = 0; cc < 4; cc++) {
        int k = col0 + cc;
        float sk = 0.f, sq = 0.f;
#pragma unroll
        for (int s = 0; s < NSL; s++) {
            sk += sumsN[s * 64 + k];
            sq += sumsqN[s * 64 + k];
        }
        float mu = sk * (1.f / NN);
        float var = sq * (1.f / NN) - mu * mu;
        mean[cc] = mu;
        rstd[cc] = rsqrtf(var + 1e-5f);
        gv[cc] = gamma[k];
        bv[cc] = beta[k];
    }
    int row = blockIdx.x * 16 + (tx >> 4);
    int rstride = gridDim.x * 16;
    for (int n = row; n < NN; n += rstride) {
        float4 x4 = *(const float4*)(agg + (size_t)n * 64 + col0);
        float y[4] = {x4.x, x4.y, x4.z, x4.w};
#pragma unroll
        for (int cc = 0; cc < 4; cc++) {
            float x = fmaxf(y[cc], 0.f);
            y[cc] = gv[cc] * (x - mean[cc]) * rstd[cc] + bv[cc];
        }
        if (shortcut) {
            float4 h4 = *(const float4*)(h_old + (size_t)n * 64 + col0);
            y[0] += h4.x; y[1] += h4.y; y[2] += h4.z; y[3] += h4.w;
        }
        *(float4*)(h_new + (size_t)n * 64 + col0) = make_float4(y[0], y[1], y[2], y[3]);
        float2 pk;
        ((__half2*)&pk)[0] = __floats2half2_rn(y[0], y[1]);
        ((__half2*)&pk)[1] = __floats2half2_rn(y[2], y[3]);
        *(float2*)(h16_out + (size_t)n * 64 + col0) = pk;
    }
    if (blockIdx.x == 0)
        classifier_body(tx, sumsN, sumsqN, XgN, gcnt, Pold, gamma, beta,
                        cW1, cb1, cg1, cbt1, cW2, cb2, logits, shortcut);
}

// Layer 2: h_new never consumed -> classifier only (1 block).
__global__ __launch_bounds__(256) void classifier_only_k(
        const float* __restrict__ sumsN, const float* __restrict__ sumsqN,
        const float* __restrict__ XgN, const int* __restrict__ gcnt,
        float* __restrict__ Pold,
        const float* __restrict__ gamma, const float* __restrict__ beta,
        const float* __restrict__ cW1, const float* __restrict__ cb1,
        const float* __restrict__ cg1, const float* __restrict__ cbt1,
        const float* __restrict__ cW2, const float* __restrict__ cb2,
        float* __restrict__ logits) {
    classifier_body(threadIdx.x, sumsN, sumsqN, XgN, gcnt, Pold, gamma, beta,
                    cW1, cb1, cg1, cbt1, cW2, cb2, logits, 1);
}

// ---------------------------------------------------------------------------
extern "C" void kernel_launch(void* const* d_in, const int* in_sizes, int n_in,
                              void* d_out, int out_size, void* d_ws, size_t ws_size,
                              hipStream_t stream) {
    const float* feature = (const float*)d_in[0];
    const float* cemb    = (const float*)d_in[1];
    const int*   src     = (const int*)d_in[2];
    const int*   dst     = (const int*)d_in[3];
    const int*   gids    = (const int*)d_in[4];
    const float* W[3]    = {(const float*)d_in[5], (const float*)d_in[6], (const float*)d_in[7]};
    const float* gam[3]  = {(const float*)d_in[8], (const float*)d_in[10], (const float*)d_in[12]};
    const float* bet[3]  = {(const float*)d_in[9], (const float*)d_in[11], (const float*)d_in[13]};
    const float* cW1  = (const float*)d_in[14];
    const float* cb1  = (const float*)d_in[15];
    const float* cg1  = (const float*)d_in[16];
    const float* cbt1 = (const float*)d_in[17];
    const float* cW2  = (const float*)d_in[18];
    const float* cb2  = (const float*)d_in[19];
    float* out = (float*)d_out;

    // workspace layout (4-byte units)
    float* ws       = (float*)d_ws;
    float* dnorm_d  = ws;                          // NE*8 = 3.2M
    float* bufX     = dnorm_d + (size_t)NE * 8;    // NN*64
    float* bufY     = bufX + (size_t)NN * 64;      // NN*64
    float* statsAll = bufY + (size_t)NN * 64;      // 3*STATS_F (zeroed in init)
    float* Pold     = statsAll + 3 * STATS_F;      // 1024 (persists across layers)
    int*   cnt      = (int*)(Pold + 1024);         // NN
    int*   gcnt     = cnt + NN;                    // 16
    int*   cur      = gcnt + 16;                   // NN
    int*   dstoff   = cur + NN;                    // NN+1 (pad +8)
    int*   bsum     = dstoff + NN + 8;             // 128
    int*   boff     = bsum + 128;                  // 128
    int*   src_d    = boff + 128;                  // NE
    __half* h16     = (__half*)(src_d + NE);       // NN*64 halfs
    __half* Wt16    = (__half*)((float*)(src_d + NE) + (size_t)NN * 32);  // 3*64*512 halfs

    hipMemsetAsync(cnt, 0, NN * sizeof(int), stream);

    init_hist_k<<<(NE + 255) / 256, 256, 0, stream>>>(dst, cnt, feature, h16,
                                                      W[0], W[1], W[2], Wt16,
                                                      statsAll, out, gids, gcnt);
    scan_part_k<<<SCAN_NB, 256, 0, stream>>>(cnt, bsum);
    scan_mid_k<<<1, 128, 0, stream>>>(bsum, boff, dstoff);
    scan_final_k<<<SCAN_NB, 256, 0, stream>>>(cnt, boff, dstoff, cur);
    scatter_k<<<(NE + 255) / 256, 256, 0, stream>>>(src, dst, cemb, cur, src_d, dnorm_d);

    const float* h_old = feature;
    float* bufs[2] = {bufX, bufY};
    for (int l = 0; l < 3; l++) {
        float* agg    = bufs[l & 1];
        float* sumsN  = statsAll + (size_t)l * STATS_F;
        float* sumsqN = sumsN + NSL * 64;
        float* XgN    = sumsqN + NSL * 64;

        edge_gemm_k<<<(NN + 15) / 16, 256, 0, stream>>>(src_d, dstoff, dnorm_d, h16,
                                                        Wt16 + (size_t)l * 64 * 512,
                                                        gids, agg, sumsN, sumsqN, XgN);
        if (l < 2) {
            bn_apply_k<<<1024, 256, 0, stream>>>(agg, h_old, sumsN, sumsqN, gam[l], bet[l],
                                                 agg, h16, l > 0, XgN, gcnt, Pold,
                                                 cW1, cb1, cg1, cbt1, cW2, cb2, out);
        } else {
            classifier_only_k<<<1, 256, 0, stream>>>(sumsN, sumsqN, XgN, gcnt, Pold,
                                                     gam[l], bet[l],
                                                     cW1, cb1, cg1, cbt1, cW2, cb2, out);
        }
        h_old = agg;
    }
}